// Round 1
// baseline (419.572 us; speedup 1.0000x reference)
//
#include <hip/hip_runtime.h>

// DetectionLayer: decode anchors + threshold-mask rows.
// out[r][0:2] = in[r][0:2] * an[r][2:4] + an[r][0:2]
// out[r][2:4] = exp(in[r][2:4]) * an[r][2:4]
// out[r][4:]  = in[r][4:]
// row zeroed when in[r][5] <= 0.5
// Memory-bound: ~1.39 GB total traffic -> ~221 us floor @ 6.3 TB/s.

#ifndef DET_C
#define DET_C 85u
#endif

__global__ __launch_bounds__(256) void DetectionLayer_kernel(
    const float* __restrict__ in,       // [N*C]
    const float* __restrict__ anchors,  // [N*4]
    float* __restrict__ out,            // [N*C]
    unsigned int n_elem,                // N*C
    unsigned int n4)                    // n_elem/4
{
    const unsigned int stride = gridDim.x * blockDim.x;
    unsigned int tid = blockIdx.x * blockDim.x + threadIdx.x;

    for (unsigned int i4 = tid; i4 < n4; i4 += stride) {
        const unsigned int base = i4 * 4u;
        float4 v = reinterpret_cast<const float4*>(in)[i4];
        float vv[4] = {v.x, v.y, v.z, v.w};

        unsigned int r = base / DET_C;          // compile-time 85 -> magic mul
        unsigned int c = base - r * DET_C;
        bool cond = in[r * DET_C + 5u] > 0.5f;

        float o[4];
#pragma unroll
        for (int k = 0; k < 4; ++k) {
            float val = vv[k];
            float dec;
            if (c < 4u) {
                // anchors row: 16B-aligned float4
                float4 an = reinterpret_cast<const float4*>(anchors)[r];
                float aa[4] = {an.x, an.y, an.z, an.w};
                if (c < 2u) {
                    dec = val * aa[2u + c] + aa[c];       // pred_yx
                } else {
                    dec = expf(val) * aa[c];              // pred_hw
                }
            } else {
                dec = val;                                 // passthrough
            }
            o[k] = cond ? dec : 0.0f;

            // advance (r,c); reload cond when crossing a row boundary
            if (++c == DET_C) {
                c = 0u;
                ++r;
                cond = in[r * DET_C + 5u] > 0.5f;
            }
        }

        reinterpret_cast<float4*>(out)[i4] =
            make_float4(o[0], o[1], o[2], o[3]);
    }

    // scalar tail (n_elem not divisible by 4 — not hit for N*C=170M, kept for safety)
    for (unsigned int i = n4 * 4u + tid; i < n_elem; i += stride) {
        unsigned int r = i / DET_C;
        unsigned int c = i - r * DET_C;
        bool cond = in[r * DET_C + 5u] > 0.5f;
        float val = in[i];
        float dec;
        if (c < 2u) {
            dec = val * anchors[r * 4u + 2u + c] + anchors[r * 4u + c];
        } else if (c < 4u) {
            dec = expf(val) * anchors[r * 4u + c];
        } else {
            dec = val;
        }
        out[i] = cond ? dec : 0.0f;
    }
}

extern "C" void kernel_launch(void* const* d_in, const int* in_sizes, int n_in,
                              void* d_out, int out_size, void* d_ws, size_t ws_size,
                              hipStream_t stream) {
    const float* in      = (const float*)d_in[0];   // [N, 85] fp32
    const float* anchors = (const float*)d_in[1];   // [N, 4]  fp32
    float* out = (float*)d_out;

    const unsigned int n_elem = (unsigned int)in_sizes[0];   // N*C
    const unsigned int n4 = n_elem / 4u;

    const int block = 256;
    unsigned int want = (n4 + block - 1) / block;
    unsigned int grid = want < 2048u ? (want ? want : 1u) : 2048u;

    DetectionLayer_kernel<<<grid, block, 0, stream>>>(in, anchors, out, n_elem, n4);
}